// Round 4
// baseline (190.865 us; speedup 1.0000x reference)
//
#include <hip/hip_runtime.h>

// Token reorderer: stable counting sort by expert id (64 experts).
// Outputs (float32, concatenated): [0,N) sorted scores, [N,2N) permutation,
// [2N,2N+64) per-expert counts.
//
// R4: decoupled-lookback single-data-pass sort (plain launches, no grid sync):
//   memset(state)  ->  hist (LDS-atomic totals)  ->  sort (ballots ONCE +
//   lookback for cross-block per-expert prefix + LDS sort + coalesced out).

#define TILE 4096          // elements per block (256 threads, 4 waves)
#define WCH  1024          // elements per wave
#define RND  16            // rounds of 64 per wave
#define FAGG (1u << 30)
#define FPRE (2u << 30)
#define VALM 0x3FFFFFFFu

__device__ __forceinline__ unsigned long long match_mask(
    unsigned key,
    unsigned long long b0, unsigned long long b1, unsigned long long b2,
    unsigned long long b3, unsigned long long b4, unsigned long long b5,
    unsigned long long am) {
  unsigned long long m = am;
  m &= (key & 1u)  ? b0 : ~b0;
  m &= (key & 2u)  ? b1 : ~b1;
  m &= (key & 4u)  ? b2 : ~b2;
  m &= (key & 8u)  ? b3 : ~b3;
  m &= (key & 16u) ? b4 : ~b4;
  m &= (key & 32u) ? b5 : ~b5;
  return m;
}

// Kernel 1: global expert totals via per-wave LDS-atomic histograms.
__global__ __launch_bounds__(256) void hist_totals_kernel(
    const int* __restrict__ idx, unsigned* __restrict__ totals, int N) {
  __shared__ unsigned h[4][64];
  int wave = threadIdx.x >> 6;
  int lane = threadIdx.x & 63;
  h[wave][lane] = 0;
  __syncthreads();

  int gid = blockIdx.x * 256 + threadIdx.x;
  int stride = gridDim.x * 256;
  int nv = N >> 2;
  const int4* v = (const int4*)idx;
  for (int j = gid; j < nv; j += stride) {
    int4 x = v[j];
    atomicAdd(&h[wave][((unsigned)x.x) & 63u], 1u);
    atomicAdd(&h[wave][((unsigned)x.y) & 63u], 1u);
    atomicAdd(&h[wave][((unsigned)x.z) & 63u], 1u);
    atomicAdd(&h[wave][((unsigned)x.w) & 63u], 1u);
  }
  int base = nv << 2;
  if (gid < N - base) atomicAdd(&h[wave][((unsigned)idx[base + gid]) & 63u], 1u);
  __syncthreads();

  if (threadIdx.x < 64) {
    unsigned s = h[0][lane] + h[1][lane] + h[2][lane] + h[3][lane];
    if (s) atomicAdd(&totals[lane], s);
  }
}

// Kernel 2: ballot pass (once) + decoupled lookback + LDS sort + write-out.
__global__ __launch_bounds__(256) void sort_kernel(
    const int* __restrict__ idx, const float* __restrict__ scores,
    const unsigned* __restrict__ totals, unsigned* __restrict__ state,
    float* __restrict__ out_scores, float* __restrict__ out_idx,
    float* __restrict__ out_counts, int N, int nb) {
  __shared__ unsigned shc[4][64];   // per-wave per-expert counts
  __shared__ unsigned dbase[64];    // global dest = dbase[e] + local pos
  __shared__ float    ssc[TILE];    // staged scores (expert-grouped)
  __shared__ unsigned spk[TILE];    // staged (index<<6)|expert

  const int wave = threadIdx.x >> 6;
  const int lane = threadIdx.x & 63;
  const unsigned long long lt = (1ull << lane) - 1ull;

  long long start = (long long)blockIdx.x * TILE + (long long)wave * WCH;
  long long remain = (long long)N - start;
  int full = 0;
  if (remain >= WCH) full = RND;
  else if (remain > 0) full = (int)(remain >> 6);
  bool hastail = (full < RND) && (remain > (long long)full * 64);

  // ---- Phase A: single ballot pass; pack (rank, cnt, e) 8b/round ----
  unsigned rank_pk[4] = {0, 0, 0, 0};
  unsigned cnt_pk[4]  = {0, 0, 0, 0};
  unsigned e_pk[4]    = {0, 0, 0, 0};
  unsigned wtotal = 0;

  #pragma unroll 4
  for (int r = 0; r < full; ++r) {
    long long i = start + (long long)r * 64 + lane;
    unsigned e = ((unsigned)idx[i]) & 63u;
    unsigned long long b0 = __ballot(e & 1u);
    unsigned long long b1 = __ballot(e & 2u);
    unsigned long long b2 = __ballot(e & 4u);
    unsigned long long b3 = __ballot(e & 8u);
    unsigned long long b4 = __ballot(e & 16u);
    unsigned long long b5 = __ballot(e & 32u);
    unsigned long long ms = match_mask(e, b0, b1, b2, b3, b4, b5, ~0ull);
    unsigned long long ml = match_mask((unsigned)lane, b0, b1, b2, b3, b4, b5, ~0ull);
    unsigned rank = (unsigned)__popcll(ms & lt);
    unsigned cnt  = (unsigned)__popcll(ml);
    int q = r >> 2, sh = (r & 3) * 8;
    rank_pk[q] |= rank << sh;
    cnt_pk[q]  |= cnt << sh;
    e_pk[q]    |= e << sh;
    wtotal += cnt;
  }
  if (hastail) {
    int r = full;
    long long i = start + (long long)r * 64 + lane;
    bool valid = i < (long long)N;
    unsigned long long am = __ballot(valid ? 1 : 0);
    unsigned e = valid ? (((unsigned)idx[i]) & 63u) : 0u;
    unsigned long long b0 = __ballot(e & 1u);
    unsigned long long b1 = __ballot(e & 2u);
    unsigned long long b2 = __ballot(e & 4u);
    unsigned long long b3 = __ballot(e & 8u);
    unsigned long long b4 = __ballot(e & 16u);
    unsigned long long b5 = __ballot(e & 32u);
    unsigned long long ms = match_mask(e, b0, b1, b2, b3, b4, b5, am);
    unsigned long long ml = match_mask((unsigned)lane, b0, b1, b2, b3, b4, b5, am);
    unsigned rank = (unsigned)__popcll(ms & lt);
    unsigned cnt  = (unsigned)__popcll(ml);
    int q = r >> 2, sh = (r & 3) * 8;
    rank_pk[q] |= rank << sh;
    cnt_pk[q]  |= cnt << sh;
    e_pk[q]    |= e << sh;
    wtotal += cnt;
  }
  shc[wave][lane] = wtotal;
  __syncthreads();

  // ---- Phase B: block-local cursors (all waves, redundantly) ----
  unsigned c0 = shc[0][lane], c1 = shc[1][lane], c2 = shc[2][lane], c3 = shc[3][lane];
  unsigned bc = c0 + c1 + c2 + c3;  // block aggregate for expert==lane

  // publish aggregate as early as possible (wave 0)
  if (threadIdx.x < 64) {
    __hip_atomic_store(&state[(size_t)blockIdx.x * 64 + lane], (bc & VALM) | FAGG,
                       __ATOMIC_RELAXED, __HIP_MEMORY_SCOPE_AGENT);
  }

  unsigned sum = bc;
  #pragma unroll
  for (int d = 1; d < 64; d <<= 1) {
    unsigned nv = __shfl_up(sum, d, 64);
    if (lane >= d) sum += nv;
  }
  unsigned local_start = sum - bc;
  unsigned running = local_start + (wave > 0 ? c0 : 0u) + (wave > 1 ? c1 : 0u) +
                     (wave > 2 ? c2 : 0u);

  // ---- Lookback (wave 0 only; waves 1-3 proceed to Phase C) ----
  if (threadIdx.x < 64) {
    unsigned ex = 0;
    int p = (int)blockIdx.x - 1;
    while (p >= 0) {
      unsigned s;
      do {
        s = __hip_atomic_load(&state[(size_t)p * 64 + lane],
                              __ATOMIC_RELAXED, __HIP_MEMORY_SCOPE_AGENT);
      } while ((s & (FAGG | FPRE)) == 0);
      ex += s & VALM;
      if (s & FPRE) break;
      --p;
    }
    __hip_atomic_store(&state[(size_t)blockIdx.x * 64 + lane],
                       ((ex + bc) & VALM) | FPRE,
                       __ATOMIC_RELAXED, __HIP_MEMORY_SCOPE_AGENT);
    // cross-expert exclusive scan of totals -> expert segment starts
    unsigned tot = totals[lane];
    unsigned s2 = tot;
    #pragma unroll
    for (int d = 1; d < 64; d <<= 1) {
      unsigned nv = __shfl_up(s2, d, 64);
      if (lane >= d) s2 += nv;
    }
    unsigned estart = s2 - tot;
    dbase[lane] = estart + ex - local_start;  // u32 wraparound ok
    if (blockIdx.x == 0) out_counts[lane] = (float)tot;  // output 2
  }

  // ---- Phase C: stable scatter into LDS (unpack registers; no re-ballot) ----
  #pragma unroll 4
  for (int r = 0; r < full; ++r) {
    long long i = start + (long long)r * 64 + lane;
    float s = scores[i];
    int q = r >> 2, sh = (r & 3) * 8;
    unsigned e    = (e_pk[q] >> sh) & 0xffu;
    unsigned rank = (rank_pk[q] >> sh) & 0xffu;
    unsigned cnt  = (cnt_pk[q] >> sh) & 0xffu;
    unsigned old = (unsigned)__shfl((int)running, (int)e, 64);
    unsigned pos = old + rank;
    running += cnt;
    ssc[pos] = s;
    spk[pos] = (((unsigned)i) << 6) | e;  // i < 2^23
  }
  if (hastail) {
    int r = full;
    long long i = start + (long long)r * 64 + lane;
    bool valid = i < (long long)N;
    float s = valid ? scores[i] : 0.0f;
    int q = r >> 2, sh = (r & 3) * 8;
    unsigned e    = (e_pk[q] >> sh) & 0xffu;
    unsigned rank = (rank_pk[q] >> sh) & 0xffu;
    unsigned cnt  = (cnt_pk[q] >> sh) & 0xffu;
    unsigned old = (unsigned)__shfl((int)running, (int)e, 64);
    unsigned pos = old + rank;
    running += cnt;
    if (valid) {
      ssc[pos] = s;
      spk[pos] = (((unsigned)i) << 6) | e;
    }
  }
  __syncthreads();

  // ---- Phase D: coalesced write-out ----
  {
    long long bstart = (long long)blockIdx.x * TILE;
    long long rem = (long long)N - bstart;
    int bvalid = rem < TILE ? (int)rem : TILE;
    for (int j = threadIdx.x; j < bvalid; j += 256) {
      unsigned p = spk[j];
      unsigned e = p & 63u;
      unsigned d = dbase[e] + (unsigned)j;
      out_scores[d] = ssc[j];
      out_idx[d] = (float)(p >> 6);
    }
  }
}

extern "C" void kernel_launch(void* const* d_in, const int* in_sizes, int n_in,
                              void* d_out, int out_size, void* d_ws, size_t ws_size,
                              hipStream_t stream) {
  const float* scores = (const float*)d_in[0];
  const int* idx = (const int*)d_in[1];
  int N = in_sizes[0];  // 8388608

  float* out_scores = (float*)d_out;
  float* out_idx = out_scores + N;
  float* out_counts = out_idx + N;

  int nb = (N + TILE - 1) / TILE;                 // 2048
  unsigned* state = (unsigned*)d_ws;              // [nb*64] lookback state
  unsigned* totals = state + (size_t)nb * 64;     // [64]

  // zero state flags + totals (d_ws is poisoned 0xAA before every call)
  hipMemsetAsync(d_ws, 0, (size_t)(nb * 64 + 64) * sizeof(unsigned), stream);

  hist_totals_kernel<<<512, 256, 0, stream>>>(idx, totals, N);
  sort_kernel<<<nb, 256, 0, stream>>>(idx, scores, totals, state,
                                      out_scores, out_idx, out_counts, N, nb);
}

// Round 5
// 158.680 us; speedup vs baseline: 1.2028x; 1.2028x over previous
//
#include <hip/hip_runtime.h>

// Token reorderer: stable counting sort by expert id (64 experts).
// Outputs (float32, concatenated): [0,N) sorted scores, [N,2N) permutation,
// [2N,2N+64) per-expert counts.
//
// R5: independent 3-kernel structure (R4's lookback spin cost more than it
// saved). Changes vs R2:
//   - hist: LDS-atomic histogram (no ballots)  ~50us -> ~12us
//   - scatter: TILE 4096->2048 (LDS 35->17KB, 4->8 blocks/CU) + single
//     ballot pass with packed (rank,cnt,e) registers (R4-proven).

#define TILE 2048          // elements per tile (256 threads, 4 waves)
#define WCH  512           // elements per wave
#define RND  8             // rounds of 64 per wave

__device__ __forceinline__ unsigned long long match_mask(
    unsigned key,
    unsigned long long b0, unsigned long long b1, unsigned long long b2,
    unsigned long long b3, unsigned long long b4, unsigned long long b5,
    unsigned long long am) {
  unsigned long long m = am;
  m &= (key & 1u)  ? b0 : ~b0;
  m &= (key & 2u)  ? b1 : ~b1;
  m &= (key & 4u)  ? b2 : ~b2;
  m &= (key & 8u)  ? b3 : ~b3;
  m &= (key & 16u) ? b4 : ~b4;
  m &= (key & 32u) ? b5 : ~b5;
  return m;
}

// Kernel 1: per-tile expert histogram via LDS atomics -> countsT[e][tile].
__global__ __launch_bounds__(256) void hist_kernel(
    const int* __restrict__ idx, unsigned* __restrict__ countsT,
    int N, int nb) {
  __shared__ unsigned h[4][64];
  int wave = threadIdx.x >> 6;
  int lane = threadIdx.x & 63;
  h[wave][lane] = 0;
  __syncthreads();

  long long base = (long long)blockIdx.x * TILE;
  long long rem = (long long)N - base;
  if (rem >= TILE) {
    const int4* v = (const int4*)(idx + base);
    #pragma unroll
    for (int k = 0; k < TILE / 1024; ++k) {
      int4 x = v[threadIdx.x + k * 256];
      atomicAdd(&h[wave][((unsigned)x.x) & 63u], 1u);
      atomicAdd(&h[wave][((unsigned)x.y) & 63u], 1u);
      atomicAdd(&h[wave][((unsigned)x.z) & 63u], 1u);
      atomicAdd(&h[wave][((unsigned)x.w) & 63u], 1u);
    }
  } else if (rem > 0) {
    for (int j = threadIdx.x; j < (int)rem; j += 256)
      atomicAdd(&h[wave][((unsigned)idx[base + j]) & 63u], 1u);
  }
  __syncthreads();
  if (threadIdx.x < 64) {
    countsT[(size_t)threadIdx.x * nb + blockIdx.x] =
        h[0][threadIdx.x] + h[1][threadIdx.x] + h[2][threadIdx.x] + h[3][threadIdx.x];
  }
}

// Kernel 2: per-expert exclusive scan over tiles (in place) + totals.
__global__ __launch_bounds__(256) void scan_kernel(
    unsigned* __restrict__ countsT, unsigned* __restrict__ totals,
    float* __restrict__ out_counts, int nb) {
  int e = blockIdx.x;   // 0..63
  int t = threadIdx.x;  // 0..255
  unsigned* row = countsT + (size_t)e * nb;
  int per = (nb + 255) >> 8;
  int base = t * per;

  unsigned s = 0;
  for (int j = 0; j < per; ++j) {
    int w = base + j;
    if (w < nb) s += row[w];
  }
  __shared__ unsigned sh[256];
  sh[t] = s;
  __syncthreads();
  for (int d = 1; d < 256; d <<= 1) {
    unsigned v = sh[t];
    unsigned a = (t >= d) ? sh[t - d] : 0u;
    __syncthreads();
    sh[t] = v + a;
    __syncthreads();
  }
  unsigned incl = sh[t];
  unsigned run = incl - s;
  for (int j = 0; j < per; ++j) {
    int w = base + j;
    if (w < nb) { unsigned v = row[w]; row[w] = run; run += v; }
  }
  if (t == 255) {
    totals[e] = incl;
    out_counts[e] = (float)incl;  // output 2
  }
}

// Kernel 3: single ballot pass (packed regs) + LDS sort + coalesced out.
__global__ __launch_bounds__(256) void scatter_kernel(
    const int* __restrict__ idx, const float* __restrict__ scores,
    const unsigned* __restrict__ baseT, const unsigned* __restrict__ totals,
    float* __restrict__ out_scores, float* __restrict__ out_idx,
    int N, int nb) {
  __shared__ unsigned shc[4][64];   // per-wave per-expert counts
  __shared__ unsigned dbase[64];    // global dest = dbase[e] + local pos
  __shared__ float    ssc[TILE];    // staged scores (expert-grouped)
  __shared__ unsigned spk[TILE];    // staged (index<<6)|expert

  const int wave = threadIdx.x >> 6;
  const int lane = threadIdx.x & 63;
  const unsigned long long lt = (1ull << lane) - 1ull;

  long long start = (long long)blockIdx.x * TILE + (long long)wave * WCH;
  long long remain = (long long)N - start;
  int full = 0;
  if (remain >= WCH) full = RND;
  else if (remain > 0) full = (int)(remain >> 6);
  bool hastail = (full < RND) && (remain > (long long)full * 64);

  // ---- Phase A: single ballot pass; pack (rank, cnt, e) 8b/round ----
  unsigned rank_pk[2] = {0, 0};
  unsigned cnt_pk[2]  = {0, 0};
  unsigned e_pk[2]    = {0, 0};
  unsigned wtotal = 0;

  #pragma unroll
  for (int r = 0; r < RND; ++r) {
    if (r >= full) break;
    long long i = start + (long long)r * 64 + lane;
    unsigned e = ((unsigned)idx[i]) & 63u;
    unsigned long long b0 = __ballot(e & 1u);
    unsigned long long b1 = __ballot(e & 2u);
    unsigned long long b2 = __ballot(e & 4u);
    unsigned long long b3 = __ballot(e & 8u);
    unsigned long long b4 = __ballot(e & 16u);
    unsigned long long b5 = __ballot(e & 32u);
    unsigned long long ms = match_mask(e, b0, b1, b2, b3, b4, b5, ~0ull);
    unsigned long long ml = match_mask((unsigned)lane, b0, b1, b2, b3, b4, b5, ~0ull);
    unsigned rank = (unsigned)__popcll(ms & lt);
    unsigned cnt  = (unsigned)__popcll(ml);
    int q = r >> 2, sh = (r & 3) * 8;
    rank_pk[q] |= rank << sh;
    cnt_pk[q]  |= cnt << sh;
    e_pk[q]    |= e << sh;
    wtotal += cnt;
  }
  if (hastail) {
    int r = full;
    long long i = start + (long long)r * 64 + lane;
    bool valid = i < (long long)N;
    unsigned long long am = __ballot(valid ? 1 : 0);
    unsigned e = valid ? (((unsigned)idx[i]) & 63u) : 0u;
    unsigned long long b0 = __ballot(e & 1u);
    unsigned long long b1 = __ballot(e & 2u);
    unsigned long long b2 = __ballot(e & 4u);
    unsigned long long b3 = __ballot(e & 8u);
    unsigned long long b4 = __ballot(e & 16u);
    unsigned long long b5 = __ballot(e & 32u);
    unsigned long long ms = match_mask(e, b0, b1, b2, b3, b4, b5, am);
    unsigned long long ml = match_mask((unsigned)lane, b0, b1, b2, b3, b4, b5, am);
    unsigned rank = (unsigned)__popcll(ms & lt);
    unsigned cnt  = (unsigned)__popcll(ml);
    int q = r >> 2, sh = (r & 3) * 8;
    rank_pk[q] |= rank << sh;
    cnt_pk[q]  |= cnt << sh;
    e_pk[q]    |= e << sh;
    wtotal += cnt;
  }
  shc[wave][lane] = wtotal;
  __syncthreads();

  // ---- Phase B: block-local cursors (all waves redundantly) + dbase ----
  unsigned c0 = shc[0][lane], c1 = shc[1][lane], c2 = shc[2][lane], c3 = shc[3][lane];
  unsigned bc = c0 + c1 + c2 + c3;
  unsigned sum = bc;
  #pragma unroll
  for (int d = 1; d < 64; d <<= 1) {
    unsigned nv = __shfl_up(sum, d, 64);
    if (lane >= d) sum += nv;
  }
  unsigned local_start = sum - bc;
  unsigned running = local_start + (wave > 0 ? c0 : 0u) + (wave > 1 ? c1 : 0u) +
                     (wave > 2 ? c2 : 0u);

  if (threadIdx.x < 64) {
    unsigned tot = totals[lane];
    unsigned s2 = tot;
    #pragma unroll
    for (int d = 1; d < 64; d <<= 1) {
      unsigned nv = __shfl_up(s2, d, 64);
      if (lane >= d) s2 += nv;
    }
    unsigned estart = s2 - tot;
    unsigned gb0 = baseT[(size_t)lane * nb + blockIdx.x];
    dbase[lane] = estart + gb0 - local_start;  // u32 wraparound ok
  }

  // ---- Phase C: stable scatter into LDS (unpack; no re-ballot) ----
  #pragma unroll
  for (int r = 0; r < RND; ++r) {
    if (r >= full) break;
    long long i = start + (long long)r * 64 + lane;
    float s = scores[i];
    int q = r >> 2, sh = (r & 3) * 8;
    unsigned e    = (e_pk[q] >> sh) & 0xffu;
    unsigned rank = (rank_pk[q] >> sh) & 0xffu;
    unsigned cnt  = (cnt_pk[q] >> sh) & 0xffu;
    unsigned old = (unsigned)__shfl((int)running, (int)e, 64);
    unsigned pos = old + rank;
    running += cnt;
    ssc[pos] = s;
    spk[pos] = (((unsigned)i) << 6) | e;  // i < 2^23
  }
  if (hastail) {
    int r = full;
    long long i = start + (long long)r * 64 + lane;
    bool valid = i < (long long)N;
    float s = valid ? scores[i] : 0.0f;
    int q = r >> 2, sh = (r & 3) * 8;
    unsigned e    = (e_pk[q] >> sh) & 0xffu;
    unsigned rank = (rank_pk[q] >> sh) & 0xffu;
    unsigned cnt  = (cnt_pk[q] >> sh) & 0xffu;
    unsigned old = (unsigned)__shfl((int)running, (int)e, 64);
    unsigned pos = old + rank;
    running += cnt;
    if (valid) {
      ssc[pos] = s;
      spk[pos] = (((unsigned)i) << 6) | e;
    }
  }
  __syncthreads();

  // ---- Phase D: coalesced write-out ----
  {
    long long bstart = (long long)blockIdx.x * TILE;
    long long rem = (long long)N - bstart;
    int bvalid = rem < TILE ? (int)rem : TILE;
    for (int j = threadIdx.x; j < bvalid; j += 256) {
      unsigned p = spk[j];
      unsigned e = p & 63u;
      unsigned d = dbase[e] + (unsigned)j;
      out_scores[d] = ssc[j];
      out_idx[d] = (float)(p >> 6);
    }
  }
}

extern "C" void kernel_launch(void* const* d_in, const int* in_sizes, int n_in,
                              void* d_out, int out_size, void* d_ws, size_t ws_size,
                              hipStream_t stream) {
  const float* scores = (const float*)d_in[0];
  const int* idx = (const int*)d_in[1];
  int N = in_sizes[0];  // 8388608

  float* out_scores = (float*)d_out;
  float* out_idx = out_scores + N;
  float* out_counts = out_idx + N;

  int nb = (N + TILE - 1) / TILE;                 // 4096
  unsigned* countsT = (unsigned*)d_ws;            // [64][nb], scanned in place
  unsigned* totals = countsT + (size_t)64 * nb;   // [64]

  hist_kernel<<<nb, 256, 0, stream>>>(idx, countsT, N, nb);
  scan_kernel<<<64, 256, 0, stream>>>(countsT, totals, out_counts, nb);
  scatter_kernel<<<nb, 256, 0, stream>>>(idx, scores, countsT, totals,
                                         out_scores, out_idx, N, nb);
}

// Round 6
// 158.462 us; speedup vs baseline: 1.2045x; 1.0014x over previous
//
#include <hip/hip_runtime.h>

// Token reorderer: stable counting sort by expert id (64 experts).
// Outputs (float32, concatenated): [0,N) sorted scores, [N,2N) permutation,
// [2N,2N+64) per-expert counts.
//
// R6: scatter v2 — per-wave LDS regions remove the A->C barrier and the
// serial per-round cursor shfl chain; full unroll (compile-time fullt path)
// lets all 8 idx/score loads batch. hist/scan unchanged from R5.

#define TILE 2048          // elements per tile (256 threads, 4 waves)
#define WCH  512           // elements per wave (one LDS region)
#define RND  8             // rounds of 64 per wave

__device__ __forceinline__ unsigned long long match_mask(
    unsigned key,
    unsigned long long b0, unsigned long long b1, unsigned long long b2,
    unsigned long long b3, unsigned long long b4, unsigned long long b5,
    unsigned long long am) {
  unsigned long long m = am;
  m &= (key & 1u)  ? b0 : ~b0;
  m &= (key & 2u)  ? b1 : ~b1;
  m &= (key & 4u)  ? b2 : ~b2;
  m &= (key & 8u)  ? b3 : ~b3;
  m &= (key & 16u) ? b4 : ~b4;
  m &= (key & 32u) ? b5 : ~b5;
  return m;
}

// Kernel 1: per-tile expert histogram via LDS atomics -> countsT[e][tile].
__global__ __launch_bounds__(256) void hist_kernel(
    const int* __restrict__ idx, unsigned* __restrict__ countsT,
    int N, int nb) {
  __shared__ unsigned h[4][64];
  int wave = threadIdx.x >> 6;
  int lane = threadIdx.x & 63;
  h[wave][lane] = 0;
  __syncthreads();

  long long base = (long long)blockIdx.x * TILE;
  long long rem = (long long)N - base;
  if (rem >= TILE) {
    const int4* v = (const int4*)(idx + base);
    #pragma unroll
    for (int k = 0; k < TILE / 1024; ++k) {
      int4 x = v[threadIdx.x + k * 256];
      atomicAdd(&h[wave][((unsigned)x.x) & 63u], 1u);
      atomicAdd(&h[wave][((unsigned)x.y) & 63u], 1u);
      atomicAdd(&h[wave][((unsigned)x.z) & 63u], 1u);
      atomicAdd(&h[wave][((unsigned)x.w) & 63u], 1u);
    }
  } else if (rem > 0) {
    for (int j = threadIdx.x; j < (int)rem; j += 256)
      atomicAdd(&h[wave][((unsigned)idx[base + j]) & 63u], 1u);
  }
  __syncthreads();
  if (threadIdx.x < 64) {
    countsT[(size_t)threadIdx.x * nb + blockIdx.x] =
        h[0][threadIdx.x] + h[1][threadIdx.x] + h[2][threadIdx.x] + h[3][threadIdx.x];
  }
}

// Kernel 2: per-expert exclusive scan over tiles (in place) + totals.
__global__ __launch_bounds__(256) void scan_kernel(
    unsigned* __restrict__ countsT, unsigned* __restrict__ totals,
    float* __restrict__ out_counts, int nb) {
  int e = blockIdx.x;   // 0..63
  int t = threadIdx.x;  // 0..255
  unsigned* row = countsT + (size_t)e * nb;
  int per = (nb + 255) >> 8;
  int base = t * per;

  unsigned s = 0;
  for (int j = 0; j < per; ++j) {
    int w = base + j;
    if (w < nb) s += row[w];
  }
  __shared__ unsigned sh[256];
  sh[t] = s;
  __syncthreads();
  for (int d = 1; d < 256; d <<= 1) {
    unsigned v = sh[t];
    unsigned a = (t >= d) ? sh[t - d] : 0u;
    __syncthreads();
    sh[t] = v + a;
    __syncthreads();
  }
  unsigned incl = sh[t];
  unsigned run = incl - s;
  for (int j = 0; j < per; ++j) {
    int w = base + j;
    if (w < nb) { unsigned v = row[w]; row[w] = run; run += v; }
  }
  if (t == 255) {
    totals[e] = incl;
    out_counts[e] = (float)incl;  // output 2
  }
}

// Kernel 3: per-wave-region LDS sort.
//   Phase A: ballots once (fully unrolled), pack (rank,cnt,e) 8b/round.
//   Wave-local shfl scan + register round-prefix -> independent cursors.
//   Phase C: scatter into wave's own 512-slot LDS quarter (NO barrier first).
//   Then one barrier, per-(wave,expert) dest table, barrier, coalesced out.
__global__ __launch_bounds__(256, 8) void scatter_kernel(
    const int* __restrict__ idx, const float* __restrict__ scores,
    const unsigned* __restrict__ baseT, const unsigned* __restrict__ totals,
    float* __restrict__ out_scores, float* __restrict__ out_idx,
    int N, int nb) {
  __shared__ float    ssc[TILE];    // staged scores (per-wave expert-grouped)
  __shared__ unsigned spk[TILE];    // staged (index<<6)|expert
  __shared__ unsigned shc[4][64];   // per-wave per-expert counts
  __shared__ unsigned table[4][64]; // global dest = table[w][e] + lds_pos

  const int wave = threadIdx.x >> 6;
  const int lane = threadIdx.x & 63;
  const unsigned long long lt = (1ull << lane) - 1ull;

  const long long start = (long long)blockIdx.x * TILE + (long long)wave * WCH;
  const bool fullt = ((long long)(blockIdx.x + 1) * TILE) <= (long long)N;

  unsigned rank_pk[2] = {0, 0};
  unsigned cnt_pk[2]  = {0, 0};
  unsigned e_pk[2]    = {0, 0};
  unsigned wtotal = 0;

  // ---- Phase A: ballot pass (once) ----
  if (fullt) {
    #pragma unroll
    for (int r = 0; r < RND; ++r) {
      long long i = start + r * 64 + lane;
      unsigned e = ((unsigned)idx[i]) & 63u;
      unsigned long long b0 = __ballot(e & 1u);
      unsigned long long b1 = __ballot(e & 2u);
      unsigned long long b2 = __ballot(e & 4u);
      unsigned long long b3 = __ballot(e & 8u);
      unsigned long long b4 = __ballot(e & 16u);
      unsigned long long b5 = __ballot(e & 32u);
      unsigned long long ms = match_mask(e, b0, b1, b2, b3, b4, b5, ~0ull);
      unsigned long long ml = match_mask((unsigned)lane, b0, b1, b2, b3, b4, b5, ~0ull);
      unsigned rank = (unsigned)__popcll(ms & lt);
      unsigned cnt  = (unsigned)__popcll(ml);
      const int q = r >> 2, sh = (r & 3) * 8;
      rank_pk[q] |= rank << sh;
      cnt_pk[q]  |= cnt << sh;
      e_pk[q]    |= e << sh;
      wtotal += cnt;
    }
  } else {
    // partial tile: mark all slots invalid first (holes allowed in regions)
    for (int j = threadIdx.x; j < TILE; j += 256) spk[j] = 0xFFFFFFFFu;
    __syncthreads();
    for (int r = 0; r < RND; ++r) {
      long long i = start + (long long)r * 64 + lane;
      bool valid = i < (long long)N;
      unsigned long long am = __ballot(valid ? 1 : 0);
      unsigned e = valid ? (((unsigned)idx[i]) & 63u) : 0u;
      unsigned long long b0 = __ballot(e & 1u);
      unsigned long long b1 = __ballot(e & 2u);
      unsigned long long b2 = __ballot(e & 4u);
      unsigned long long b3 = __ballot(e & 8u);
      unsigned long long b4 = __ballot(e & 16u);
      unsigned long long b5 = __ballot(e & 32u);
      unsigned long long ms = match_mask(e, b0, b1, b2, b3, b4, b5, am);
      unsigned long long ml = match_mask((unsigned)lane, b0, b1, b2, b3, b4, b5, am);
      unsigned rank = (unsigned)__popcll(ms & lt);
      unsigned cnt  = (unsigned)__popcll(ml);
      const int q = r >> 2, sh = (r & 3) * 8;
      rank_pk[q] |= rank << sh;
      cnt_pk[q]  |= cnt << sh;
      e_pk[q]    |= (valid ? e : 0u) << sh;
      wtotal += cnt;
    }
  }

  // ---- Wave-local expert scan (no barrier): region start for expert==lane ----
  unsigned sum = wtotal;
  #pragma unroll
  for (int d = 1; d < 64; d <<= 1) {
    unsigned nv = __shfl_up(sum, d, 64);
    if (lane >= d) sum += nv;
  }
  unsigned ws_l = (unsigned)(wave * WCH) + (sum - wtotal);

  // per-round cursor for expert==lane (register prefix; breaks shfl chain)
  unsigned cur[RND];
  {
    unsigned acc = ws_l;
    #pragma unroll
    for (int r = 0; r < RND; ++r) {
      cur[r] = acc;
      acc += (cnt_pk[r >> 2] >> ((r & 3) * 8)) & 0xffu;
    }
  }

  // ---- Phase C: scatter into this wave's LDS quarter (independent shfls) ----
  if (fullt) {
    #pragma unroll
    for (int r = 0; r < RND; ++r) {
      long long i = start + r * 64 + lane;
      float s = scores[i];
      const int q = r >> 2, sh = (r & 3) * 8;
      unsigned e    = (e_pk[q] >> sh) & 0xffu;
      unsigned rank = (rank_pk[q] >> sh) & 0xffu;
      unsigned pos = (unsigned)__shfl((int)cur[r], (int)e, 64) + rank;
      ssc[pos] = s;
      spk[pos] = (((unsigned)i) << 6) | e;  // i < 2^23
    }
  } else {
    for (int r = 0; r < RND; ++r) {
      long long i = start + (long long)r * 64 + lane;
      bool valid = i < (long long)N;
      float s = valid ? scores[i] : 0.0f;
      const int q = r >> 2, sh = (r & 3) * 8;
      unsigned e    = (e_pk[q] >> sh) & 0xffu;
      unsigned rank = (rank_pk[q] >> sh) & 0xffu;
      unsigned pos = (unsigned)__shfl((int)cur[r], (int)e, 64) + rank;
      if (valid) {
        ssc[pos] = s;
        spk[pos] = (((unsigned)i) << 6) | e;
      }
    }
  }

  shc[wave][lane] = wtotal;
  __syncthreads();

  // ---- Dest table: wave w computes table[w][e] ----
  {
    unsigned tot = totals[lane];
    unsigned s2 = tot;
    #pragma unroll
    for (int d = 1; d < 64; d <<= 1) {
      unsigned nv = __shfl_up(s2, d, 64);
      if (lane >= d) s2 += nv;
    }
    unsigned estart = s2 - tot;                        // expert segment start
    unsigned gb0 = baseT[(size_t)lane * nb + blockIdx.x];  // tiles-before prefix

    unsigned c = shc[wave][lane];
    unsigned s3 = c;
    #pragma unroll
    for (int d = 1; d < 64; d <<= 1) {
      unsigned nv = __shfl_up(s3, d, 64);
      if (lane >= d) s3 += nv;
    }
    unsigned wse = (unsigned)(wave * WCH) + (s3 - c);  // region start of (w,e)

    unsigned wpre = 0;
    for (int w2 = 0; w2 < wave; ++w2) wpre += shc[w2][lane];

    table[wave][lane] = estart + gb0 + wpre - wse;     // u32 wraparound ok
  }
  __syncthreads();

  // ---- Phase D: coalesced write-out ----
  if (fullt) {
    for (int j = threadIdx.x; j < TILE; j += 256) {
      unsigned p = spk[j];
      unsigned e = p & 63u;
      int w = j >> 9;  // WCH=512
      unsigned d = table[w][e] + (unsigned)j;
      out_scores[d] = ssc[j];
      out_idx[d] = (float)(p >> 6);
    }
  } else {
    for (int j = threadIdx.x; j < TILE; j += 256) {
      unsigned p = spk[j];
      if (p == 0xFFFFFFFFu) continue;
      unsigned e = p & 63u;
      int w = j >> 9;
      unsigned d = table[w][e] + (unsigned)j;
      out_scores[d] = ssc[j];
      out_idx[d] = (float)(p >> 6);
    }
  }
}

extern "C" void kernel_launch(void* const* d_in, const int* in_sizes, int n_in,
                              void* d_out, int out_size, void* d_ws, size_t ws_size,
                              hipStream_t stream) {
  const float* scores = (const float*)d_in[0];
  const int* idx = (const int*)d_in[1];
  int N = in_sizes[0];  // 8388608

  float* out_scores = (float*)d_out;
  float* out_idx = out_scores + N;
  float* out_counts = out_idx + N;

  int nb = (N + TILE - 1) / TILE;                 // 4096
  unsigned* countsT = (unsigned*)d_ws;            // [64][nb], scanned in place
  unsigned* totals = countsT + (size_t)64 * nb;   // [64]

  hist_kernel<<<nb, 256, 0, stream>>>(idx, countsT, N, nb);
  scan_kernel<<<64, 256, 0, stream>>>(countsT, totals, out_counts, nb);
  scatter_kernel<<<nb, 256, 0, stream>>>(idx, scores, countsT, totals,
                                         out_scores, out_idx, N, nb);
}

// Round 7
// 144.289 us; speedup vs baseline: 1.3228x; 1.0982x over previous
//
#include <hip/hip_runtime.h>

// Token reorderer: stable counting sort by expert id (64 experts).
// Outputs (float32, concatenated): [0,N) sorted scores, [N,2N) permutation,
// [2N,2N+64) per-expert counts.
//
// R7: scatter VALU diet. Per round: ONE match_mask (ms); per-expert round
// counts via wave-private LDS tmp (write0 / write rcnt / read — same-wave DS
// ops execute in order, no atomics, no serial cross-round chain). uint2 LDS
// staging (b64 ops), dest-table scan deduplicated, totals/baseT loads hoisted.

#define TILE 2048          // elements per tile (256 threads, 4 waves)
#define WCH  512           // elements per wave (one LDS region)
#define RND  8             // rounds of 64 per wave

__device__ __forceinline__ unsigned long long match_mask(
    unsigned key,
    unsigned long long b0, unsigned long long b1, unsigned long long b2,
    unsigned long long b3, unsigned long long b4, unsigned long long b5,
    unsigned long long am) {
  unsigned long long m = am;
  m &= (key & 1u)  ? b0 : ~b0;
  m &= (key & 2u)  ? b1 : ~b1;
  m &= (key & 4u)  ? b2 : ~b2;
  m &= (key & 8u)  ? b3 : ~b3;
  m &= (key & 16u) ? b4 : ~b4;
  m &= (key & 32u) ? b5 : ~b5;
  return m;
}

// Kernel 1: per-tile expert histogram via LDS atomics -> countsT[e][tile].
__global__ __launch_bounds__(256) void hist_kernel(
    const int* __restrict__ idx, unsigned* __restrict__ countsT,
    int N, int nb) {
  __shared__ unsigned h[4][64];
  int wave = threadIdx.x >> 6;
  int lane = threadIdx.x & 63;
  h[wave][lane] = 0;
  __syncthreads();

  long long base = (long long)blockIdx.x * TILE;
  long long rem = (long long)N - base;
  if (rem >= TILE) {
    const int4* v = (const int4*)(idx + base);
    #pragma unroll
    for (int k = 0; k < TILE / 1024; ++k) {
      int4 x = v[threadIdx.x + k * 256];
      atomicAdd(&h[wave][((unsigned)x.x) & 63u], 1u);
      atomicAdd(&h[wave][((unsigned)x.y) & 63u], 1u);
      atomicAdd(&h[wave][((unsigned)x.z) & 63u], 1u);
      atomicAdd(&h[wave][((unsigned)x.w) & 63u], 1u);
    }
  } else if (rem > 0) {
    for (int j = threadIdx.x; j < (int)rem; j += 256)
      atomicAdd(&h[wave][((unsigned)idx[base + j]) & 63u], 1u);
  }
  __syncthreads();
  if (threadIdx.x < 64) {
    countsT[(size_t)threadIdx.x * nb + blockIdx.x] =
        h[0][threadIdx.x] + h[1][threadIdx.x] + h[2][threadIdx.x] + h[3][threadIdx.x];
  }
}

// Kernel 2: per-expert exclusive scan over tiles (in place) + totals.
__global__ __launch_bounds__(256) void scan_kernel(
    unsigned* __restrict__ countsT, unsigned* __restrict__ totals,
    float* __restrict__ out_counts, int nb) {
  int e = blockIdx.x;   // 0..63
  int t = threadIdx.x;  // 0..255
  unsigned* row = countsT + (size_t)e * nb;
  int per = (nb + 255) >> 8;
  int base = t * per;

  unsigned s = 0;
  for (int j = 0; j < per; ++j) {
    int w = base + j;
    if (w < nb) s += row[w];
  }
  __shared__ unsigned sh[256];
  sh[t] = s;
  __syncthreads();
  for (int d = 1; d < 256; d <<= 1) {
    unsigned v = sh[t];
    unsigned a = (t >= d) ? sh[t - d] : 0u;
    __syncthreads();
    sh[t] = v + a;
    __syncthreads();
  }
  unsigned incl = sh[t];
  unsigned run = incl - s;
  for (int j = 0; j < per; ++j) {
    int w = base + j;
    if (w < nb) { unsigned v = row[w]; row[w] = run; run += v; }
  }
  if (t == 255) {
    totals[e] = incl;
    out_counts[e] = (float)incl;  // output 2
  }
}

// Kernel 3: per-wave-region LDS sort, single match_mask per round.
__global__ __launch_bounds__(256, 8) void scatter_kernel(
    const int* __restrict__ idx, const float* __restrict__ scores,
    const unsigned* __restrict__ baseT, const unsigned* __restrict__ totals,
    float* __restrict__ out_scores, float* __restrict__ out_idx,
    int N, int nb) {
  __shared__ uint2    sdat[TILE];   // {score bits, (i<<6)|e}, expert-grouped
  __shared__ unsigned tmpc[4][64];  // wave-private per-round count transpose
  __shared__ unsigned shc[4][64];   // per-wave per-expert totals
  __shared__ unsigned table[4][64]; // global dest = table[w][e] + lds_pos

  const int wave = threadIdx.x >> 6;
  const int lane = threadIdx.x & 63;
  const unsigned long long lt = (1ull << lane) - 1ull;

  const long long start = (long long)blockIdx.x * TILE + (long long)wave * WCH;
  const bool fullt = ((long long)(blockIdx.x + 1) * TILE) <= (long long)N;

  // hoisted global loads (consumed only at table-calc time)
  const unsigned tot = totals[lane];
  const unsigned gb0 = baseT[(size_t)lane * nb + blockIdx.x];

  unsigned e_pk[2] = {0, 0};
  unsigned r_pk[2] = {0, 0};
  unsigned c_pk[2] = {0, 0};
  unsigned wtotal = 0;

  // ---- Pass 1: ballots once; counts via wave-private LDS transpose ----
  if (fullt) {
    #pragma unroll
    for (int r = 0; r < RND; ++r) {
      long long i = start + r * 64 + lane;
      unsigned e = ((unsigned)idx[i]) & 63u;
      unsigned long long b0 = __ballot(e & 1u);
      unsigned long long b1 = __ballot(e & 2u);
      unsigned long long b2 = __ballot(e & 4u);
      unsigned long long b3 = __ballot(e & 8u);
      unsigned long long b4 = __ballot(e & 16u);
      unsigned long long b5 = __ballot(e & 32u);
      unsigned long long ms = match_mask(e, b0, b1, b2, b3, b4, b5, ~0ull);
      unsigned rank = (unsigned)__popcll(ms & lt);
      unsigned rcnt = (unsigned)__popcll(ms);
      // same-wave DS ops execute in order: clear, scatter rcnt, gather count
      tmpc[wave][lane] = 0;
      tmpc[wave][e] = rcnt;
      unsigned cnt = tmpc[wave][lane];  // count of expert==lane this round
      const int q = r >> 2, sh = (r & 3) * 8;
      e_pk[q] |= e << sh;
      r_pk[q] |= rank << sh;
      c_pk[q] |= cnt << sh;
      wtotal += cnt;
    }
  } else {
    for (int j = threadIdx.x; j < TILE; j += 256) sdat[j].y = 0xFFFFFFFFu;
    __syncthreads();
    for (int r = 0; r < RND; ++r) {
      long long i = start + (long long)r * 64 + lane;
      bool valid = i < (long long)N;
      unsigned long long am = __ballot(valid ? 1 : 0);
      unsigned e = valid ? (((unsigned)idx[i]) & 63u) : 0u;
      unsigned long long b0 = __ballot(e & 1u);
      unsigned long long b1 = __ballot(e & 2u);
      unsigned long long b2 = __ballot(e & 4u);
      unsigned long long b3 = __ballot(e & 8u);
      unsigned long long b4 = __ballot(e & 16u);
      unsigned long long b5 = __ballot(e & 32u);
      unsigned long long ms = match_mask(e, b0, b1, b2, b3, b4, b5, am);
      unsigned rank = (unsigned)__popcll(ms & lt);
      unsigned rcnt = (unsigned)__popcll(ms);
      tmpc[wave][lane] = 0;
      if (valid) tmpc[wave][e] = rcnt;
      unsigned cnt = tmpc[wave][lane];
      const int q = r >> 2, sh = (r & 3) * 8;
      e_pk[q] |= e << sh;
      r_pk[q] |= rank << sh;
      c_pk[q] |= cnt << sh;
      wtotal += cnt;
    }
  }

  shc[wave][lane] = wtotal;

  // wave-region expert start (expert==lane) via shfl scan
  unsigned sum = wtotal;
  #pragma unroll
  for (int d = 1; d < 64; d <<= 1) {
    unsigned nv = __shfl_up(sum, d, 64);
    if (lane >= d) sum += nv;
  }
  const unsigned ws_l = (unsigned)(wave * WCH) + (sum - wtotal);

  // per-round cursors (register prefix; no cross-round shfl chain)
  unsigned cur[RND];
  {
    unsigned acc = ws_l;
    #pragma unroll
    for (int r = 0; r < RND; ++r) {
      cur[r] = acc;
      acc += (c_pk[r >> 2] >> ((r & 3) * 8)) & 0xffu;
    }
  }

  __syncthreads();  // shc visible to all waves

  // ---- Dest table (reuses ws_l scan; tot/gb0 already in flight) ----
  {
    unsigned s2 = tot;
    #pragma unroll
    for (int d = 1; d < 64; d <<= 1) {
      unsigned nv = __shfl_up(s2, d, 64);
      if (lane >= d) s2 += nv;
    }
    unsigned estart = s2 - tot;  // global start of expert==lane
    unsigned wpre = 0;
    for (int w2 = 0; w2 < wave; ++w2) wpre += shc[w2][lane];
    table[wave][lane] = estart + gb0 + wpre - ws_l;  // u32 wraparound ok
  }

  // ---- Pass 2: scatter into this wave's LDS region (b64) ----
  if (fullt) {
    #pragma unroll
    for (int r = 0; r < RND; ++r) {
      long long i = start + r * 64 + lane;
      float s = scores[i];
      const int q = r >> 2, sh = (r & 3) * 8;
      unsigned e    = (e_pk[q] >> sh) & 0xffu;
      unsigned rank = (r_pk[q] >> sh) & 0xffu;
      unsigned pos = (unsigned)__shfl((int)cur[r], (int)e, 64) + rank;
      sdat[pos] = make_uint2(__float_as_uint(s), (((unsigned)i) << 6) | e);
    }
  } else {
    for (int r = 0; r < RND; ++r) {
      long long i = start + (long long)r * 64 + lane;
      bool valid = i < (long long)N;
      float s = valid ? scores[i] : 0.0f;
      const int q = r >> 2, sh = (r & 3) * 8;
      unsigned e    = (e_pk[q] >> sh) & 0xffu;
      unsigned rank = (r_pk[q] >> sh) & 0xffu;
      unsigned pos = (unsigned)__shfl((int)cur[r], (int)e, 64) + rank;
      if (valid) {
        sdat[pos] = make_uint2(__float_as_uint(s), (((unsigned)i) << 6) | e);
      }
    }
  }
  __syncthreads();

  // ---- Phase D: coalesced write-out ----
  if (fullt) {
    #pragma unroll
    for (int k = 0; k < TILE / 256; ++k) {
      int j = threadIdx.x + k * 256;
      uint2 v = sdat[j];
      unsigned e = v.y & 63u;
      int w = j >> 9;  // WCH=512
      unsigned d = table[w][e] + (unsigned)j;
      out_scores[d] = __uint_as_float(v.x);
      out_idx[d] = (float)(v.y >> 6);
    }
  } else {
    for (int j = threadIdx.x; j < TILE; j += 256) {
      uint2 v = sdat[j];
      if (v.y == 0xFFFFFFFFu) continue;
      unsigned e = v.y & 63u;
      int w = j >> 9;
      unsigned d = table[w][e] + (unsigned)j;
      out_scores[d] = __uint_as_float(v.x);
      out_idx[d] = (float)(v.y >> 6);
    }
  }
}

extern "C" void kernel_launch(void* const* d_in, const int* in_sizes, int n_in,
                              void* d_out, int out_size, void* d_ws, size_t ws_size,
                              hipStream_t stream) {
  const float* scores = (const float*)d_in[0];
  const int* idx = (const int*)d_in[1];
  int N = in_sizes[0];  // 8388608

  float* out_scores = (float*)d_out;
  float* out_idx = out_scores + N;
  float* out_counts = out_idx + N;

  int nb = (N + TILE - 1) / TILE;                 // 4096
  unsigned* countsT = (unsigned*)d_ws;            // [64][nb], scanned in place
  unsigned* totals = countsT + (size_t)64 * nb;   // [64]

  hist_kernel<<<nb, 256, 0, stream>>>(idx, countsT, N, nb);
  scan_kernel<<<64, 256, 0, stream>>>(countsT, totals, out_counts, nb);
  scatter_kernel<<<nb, 256, 0, stream>>>(idx, scores, countsT, totals,
                                         out_scores, out_idx, N, nb);
}